// Round 11
// baseline (143.693 us; speedup 1.0000x reference)
//
#include <hip/hip_runtime.h>
#include <hip/hip_cooperative_groups.h>
#include <cstdint>

namespace coop = cooperative_groups;

#define BB 4
#define HH 2048
#define WW 2048
#define MAXT 21
#define BIGSQ 441        // MAXT^2
#define SEN (1u << 6)    // sentinel bit: quad-dist t=6 -> d>=24 -> clamps to 21

typedef float floatx4 __attribute__((ext_vector_type(4)));
typedef unsigned short u16x2 __attribute__((ext_vector_type(2)));

static __device__ __forceinline__ uint32_t umax32(uint32_t a, uint32_t b) { return a > b ? a : b; }
static __device__ __forceinline__ int imin(int a, int b) { return a < b ? a : b; }

// ---- horizontal pass, one full row (2048 px) per wave: R10-validated quad scheme ----
static __device__ __forceinline__ void hrow(const int* __restrict__ rp,
                                            uint8_t* __restrict__ dst,
                                            const int lane) {
    const int li = 63 - lane;

    uint4 q[8];
    #pragma unroll
    for (int j = 0; j < 8; ++j)
        q[j] = *(const uint4*)(rp + (j << 8) + (lane << 2));

    unsigned long long Bc[4], Bn[4], rbc[4], rbp[4];
    #pragma unroll
    for (int k = 0; k < 4; ++k) rbp[k] = 0;
    Bc[0] = __ballot(q[0].x != 0);
    Bc[1] = __ballot(q[0].y != 0);
    Bc[2] = __ballot(q[0].z != 0);
    Bc[3] = __ballot(q[0].w != 0);
    #pragma unroll
    for (int k = 0; k < 4; ++k) rbc[k] = __brevll(Bc[k]);

    #pragma unroll
    for (int j = 0; j < 8; ++j) {
        if (j < 7) {
            Bn[0] = __ballot(q[j + 1].x != 0);
            Bn[1] = __ballot(q[j + 1].y != 0);
            Bn[2] = __ballot(q[j + 1].z != 0);
            Bn[3] = __ballot(q[j + 1].w != 0);
        } else {
            Bn[0] = Bn[1] = Bn[2] = Bn[3] = 0;
        }

        int a[4], b[4], c[4], e[4];
        #pragma unroll
        for (int k = 0; k < 4; ++k) {
            unsigned long long S  = (Bc[k] >> lane) | ((Bn[k] << 1) << li);
            unsigned long long SL = (rbc[k] >> li)  | ((rbp[k] << 1) << lane);
            uint32_t s  = (uint32_t)S;
            uint32_t sl = (uint32_t)SL;
            a[k] = 4 * __builtin_ctz(s | SEN) + k;
            b[k] = 4 * __builtin_ctz((s >> 1) | SEN) + 4 + k;
            c[k] = 4 * __builtin_ctz(sl | SEN) - k;
            e[k] = 4 * __builtin_ctz((sl >> 1) | SEN) + 4 - k;
        }
        const int A3 = a[3], A2 = imin(a[2], A3), A1 = imin(a[1], A2), A0 = imin(a[0], A1);
        const int B0 = b[0], B1 = imin(B0, b[1]), B2 = imin(B1, b[2]);
        const int C0 = c[0], C1 = imin(C0, c[1]), C2 = imin(C1, c[2]), C3 = imin(C2, c[3]);
        const int E3 = e[3], E2 = imin(e[2], E3), E1 = imin(e[1], E2);

        int d0 = imin(imin(A0,               imin(C0, E1)    ), MAXT);
        int d1 = imin(imin(imin(A1, B0) - 1, imin(C1, E2) + 1), MAXT);
        int d2 = imin(imin(imin(A2, B1) - 2, imin(C2, E3) + 2), MAXT);
        int d3 = imin(imin(imin(A3, B2) - 3, C3 + 3          ), MAXT);

        uint32_t pk = (uint32_t)d0 | ((uint32_t)d1 << 8) | ((uint32_t)d2 << 16) | ((uint32_t)d3 << 24);
        *(uint32_t*)(dst + (j << 8) + (lane << 2)) = pk;

        #pragma unroll
        for (int k = 0; k < 4; ++k) {
            rbp[k] = rbc[k];
            Bc[k]  = Bn[k];
            rbc[k] = __brevll(Bn[k]);
        }
    }
}

// Cooperative fused kernel: phase 1 = hpass over 8 rows/block; grid sync;
// phase 2 = two vpass 128x64 tiles/block (R10-validated packed-u16 relax).
// XCD-chunked si mapping: each XCD's blocks produce exactly the dh row-band
// their phase-2 tiles consume -> dh write->read stays in that XCD's L2.
__global__ __launch_bounds__(256, 4) void fused_coop(const int* __restrict__ in,
                                                     uint8_t* __restrict__ dh,
                                                     float* __restrict__ out) {
    __shared__ uint16_t s[106][128];   // 27136 B
    const int tid  = threadIdx.x;
    const int lane = tid & 63;
    const int w    = tid >> 6;
    const int bid  = blockIdx.x;                 // 1024 blocks
    const int si   = (bid & 7) * 128 + (bid >> 3);   // XCD-chunked, bijective

    // ---- phase 1: rows [8*si, 8*si+8), 2 rows per wave ----
    #pragma unroll
    for (int rr = 0; rr < 2; ++rr) {
        const int row = (si << 3) + (w << 1) + rr;   // global row in [0, BB*HH)
        const int ro  = row * WW;                    // < 2^24, int32 safe
        hrow(in + ro, dh + ro, lane);
    }

    coop::this_grid().sync();

    // ---- phase 2: tiles 2*si, 2*si+1 (ti = (b*32 + y0/64)*16 + xt) ----
    for (int qq = 0; qq < 2; ++qq) {
        const int ti = (si << 1) + qq;
        const int xt = ti & 15;
        const int gt = ti >> 4;          // global y-tile: b*32 + (y0>>6)
        const int b  = gt >> 5;
        const int y0 = (gt & 31) << 6;
        const int x0 = xt << 7;
        const int base = b * (HH * WW);

        // stage: 16 dh bytes per lane-iter -> 16 squared u16 -> two b128 LDS writes
        for (int i = tid; i < 106 * 8; i += 256) {
            const int r   = i >> 3;
            const int c16 = (i & 7) << 4;
            const int gy  = y0 - 21 + r;
            uint4 pk0, pk1;
            if (gy >= 0 && gy < HH) {
                const uint8_t* p = dh + base + gy * WW + x0 + c16;
                uint4 u = *(const uint4*)p;
                #pragma unroll
                for (int h = 0; h < 4; ++h) {
                    uint32_t word = (&u.x)[h];
                    uint32_t e0 = word & 0xff, e1 = (word >> 8) & 0xff;
                    uint32_t e2 = (word >> 16) & 0xff, e3 = word >> 24;
                    uint32_t lo = (e0 * e0) | ((e1 * e1) << 16);
                    uint32_t hi = (e2 * e2) | ((e3 * e3) << 16);
                    if (h < 2) { (&pk0.x)[h * 2] = lo; (&pk0.x)[h * 2 + 1] = hi; }
                    else       { (&pk1.x)[(h - 2) * 2] = lo; (&pk1.x)[(h - 2) * 2 + 1] = hi; }
                }
            } else {
                pk0.x = pk0.y = pk0.z = pk0.w = BIGSQ | (BIGSQ << 16);
                pk1 = pk0;
            }
            *(uint4*)&s[r][c16]     = pk0;
            *(uint4*)&s[r][c16 + 8] = pk1;
        }
        __syncthreads();

        const int cg4  = (lane & 31) << 2;   // 4 adjacent cols per lane
        const int rofs = lane >> 5;          // row offset 0/1
        for (int k = 0; k < 8; ++k) {
            const int j  = (w << 4) + (k << 1) + rofs;
            const int yl = 21 + j;

            uint2 q = *(const uint2*)&s[yl][cg4];
            u16x2 V0 = __builtin_bit_cast(u16x2, q.x);
            u16x2 V1 = __builtin_bit_cast(u16x2, q.y);

            for (int d = 1; d <= MAXT; ++d) {
                const uint32_t dd = (uint32_t)(d * d);
                u16x2 M = __builtin_elementwise_max(V0, V1);
                uint32_t m32 = __builtin_bit_cast(uint32_t, M);
                uint32_t h = umax32(m32 & 0xffffu, m32 >> 16);
                if (__all(dd >= h)) break;   // further candidates >= d^2 >= current
                uint2 a  = *(const uint2*)&s[yl - d][cg4];
                uint2 bq = *(const uint2*)&s[yl + d][cg4];
                u16x2 D  = { (unsigned short)dd, (unsigned short)dd };
                u16x2 A0 = __builtin_bit_cast(u16x2, a.x),  A1 = __builtin_bit_cast(u16x2, a.y);
                u16x2 B0 = __builtin_bit_cast(u16x2, bq.x), B1 = __builtin_bit_cast(u16x2, bq.y);
                // min(A,B)+D == min(A+D, B+D); values <= 882, no u16 overflow
                V0 = __builtin_elementwise_min(V0, (u16x2)(__builtin_elementwise_min(A0, B0) + D));
                V1 = __builtin_elementwise_min(V1, (u16x2)(__builtin_elementwise_min(A1, B1) + D));
            }

            const uint32_t r0 = __builtin_bit_cast(uint32_t, V0);
            const uint32_t r1 = __builtin_bit_cast(uint32_t, V1);
            floatx4 o;
            o.x = sqrtf((float)(r0 & 0xffffu));
            o.y = sqrtf((float)(r0 >> 16));
            o.z = sqrtf((float)(r1 & 0xffffu));
            o.w = sqrtf((float)(r1 >> 16));
            floatx4* op = (floatx4*)&out[base + (y0 + j) * WW + x0 + cg4];
            __builtin_nontemporal_store(o, op);
        }
        __syncthreads();   // LDS safe before next tile's staging
    }
}

extern "C" void kernel_launch(void* const* d_in, const int* in_sizes, int n_in,
                              void* d_out, int out_size, void* d_ws, size_t ws_size,
                              hipStream_t stream) {
    const int* unt = (const int*)d_in[0];
    uint8_t* dh    = (uint8_t*)d_ws;             // BB*HH*WW bytes = 16.7 MB scratch
    float* outp    = (float*)d_out;

    void* args[] = { (void*)&unt, (void*)&dh, (void*)&outp };
    hipLaunchCooperativeKernel(reinterpret_cast<const void*>(fused_coop),
                               dim3(1024), dim3(256), args, 0, stream);
}

// Round 12
// 45.685 us; speedup vs baseline: 3.1453x; 3.1453x over previous
//
#include <hip/hip_runtime.h>
#include <cstdint>

#define BB 4
#define HH 2048
#define WW 2048
#define MAXT 21
#define BIGSQ 441        // MAXT^2
#define SEN (1u << 6)    // sentinel bit: quad-dist t=6 -> d>=24 -> clamps to 21

typedef float floatx4 __attribute__((ext_vector_type(4)));
typedef unsigned short u16x2 __attribute__((ext_vector_type(2)));
typedef unsigned int ux4 __attribute__((ext_vector_type(4)));

static __device__ __forceinline__ uint32_t umax32(uint32_t a, uint32_t b) { return a > b ? a : b; }
static __device__ __forceinline__ int imin(int a, int b) { return a < b ? a : b; }

// ---------------- Pass A: horizontal capped nearest-obstacle distance ----------------
// One wave = one full row (2048 px), uint4 NT loads (16 B = 4 px per lane), ALL
// issued before compute (sched_barrier pins the order -> one cold-HBM latency
// exposure per row, overlapped across waves). Quad-phase ballot scheme
// (R7/R10-validated): funnel-aligned masks, sentinel-capped ctz, prefix/suffix
// min combine. All indexing int32.
__global__ __launch_bounds__(256) void hpass(const int* __restrict__ in,
                                             uint8_t* __restrict__ dh) {
    const int tid  = threadIdx.x;
    const int lane = tid & 63;
    const int w    = tid >> 6;
    const int row  = (blockIdx.x << 2) + w;   // 4 rows per block; rows never cross batches
    const int ro   = row * WW;                 // < 2^24, int32 safe
    const int* rp  = in + ro;
    const int li   = 63 - lane;

    ux4 q[8];
    #pragma unroll
    for (int j = 0; j < 8; ++j)
        q[j] = __builtin_nontemporal_load((const ux4*)(rp + (j << 8) + (lane << 2)));
    __builtin_amdgcn_sched_barrier(0);   // keep all 8 loads issued upfront

    unsigned long long Bc[4], Bn[4], rbc[4], rbp[4];
    #pragma unroll
    for (int k = 0; k < 4; ++k) rbp[k] = 0;
    Bc[0] = __ballot(q[0].x != 0);
    Bc[1] = __ballot(q[0].y != 0);
    Bc[2] = __ballot(q[0].z != 0);
    Bc[3] = __ballot(q[0].w != 0);
    #pragma unroll
    for (int k = 0; k < 4; ++k) rbc[k] = __brevll(Bc[k]);

    #pragma unroll
    for (int j = 0; j < 8; ++j) {
        if (j < 7) {
            Bn[0] = __ballot(q[j + 1].x != 0);
            Bn[1] = __ballot(q[j + 1].y != 0);
            Bn[2] = __ballot(q[j + 1].z != 0);
            Bn[3] = __ballot(q[j + 1].w != 0);
        } else {
            Bn[0] = Bn[1] = Bn[2] = Bn[3] = 0;
        }

        int a[4], b[4], c[4], e[4];
        #pragma unroll
        for (int k = 0; k < 4; ++k) {
            unsigned long long S  = (Bc[k] >> lane) | ((Bn[k] << 1) << li);
            unsigned long long SL = (rbc[k] >> li)  | ((rbp[k] << 1) << lane);
            uint32_t s  = (uint32_t)S;
            uint32_t sl = (uint32_t)SL;
            a[k] = 4 * __builtin_ctz(s | SEN) + k;
            b[k] = 4 * __builtin_ctz((s >> 1) | SEN) + 4 + k;
            c[k] = 4 * __builtin_ctz(sl | SEN) - k;
            e[k] = 4 * __builtin_ctz((sl >> 1) | SEN) + 4 - k;
        }
        const int A3 = a[3], A2 = imin(a[2], A3), A1 = imin(a[1], A2), A0 = imin(a[0], A1);
        const int B0 = b[0], B1 = imin(B0, b[1]), B2 = imin(B1, b[2]);
        const int C0 = c[0], C1 = imin(C0, c[1]), C2 = imin(C1, c[2]), C3 = imin(C2, c[3]);
        const int E3 = e[3], E2 = imin(e[2], E3), E1 = imin(e[1], E2);

        int d0 = imin(imin(A0,               imin(C0, E1)    ), MAXT);
        int d1 = imin(imin(imin(A1, B0) - 1, imin(C1, E2) + 1), MAXT);
        int d2 = imin(imin(imin(A2, B1) - 2, imin(C2, E3) + 2), MAXT);
        int d3 = imin(imin(imin(A3, B2) - 3, C3 + 3          ), MAXT);

        uint32_t pk = (uint32_t)d0 | ((uint32_t)d1 << 8) | ((uint32_t)d2 << 16) | ((uint32_t)d3 << 24);
        *(uint32_t*)(dh + ro + (j << 8) + (lane << 2)) = pk;

        #pragma unroll
        for (int k = 0; k < 4; ++k) {
            rbp[k] = rbc[k];
            Bc[k]  = Bn[k];
            rbc[k] = __brevll(Bn[k]);
        }
    }
}

// ---------------- Pass B: vertical relax + sqrt (R10-validated, unchanged) ----------------
__global__ __launch_bounds__(256) void vpass(const uint8_t* __restrict__ dh,
                                             float* __restrict__ out) {
    __shared__ uint16_t s[106][128];   // 27136 B
    const int tid = threadIdx.x;
    const int bid = blockIdx.x;                   // 2048 blocks, 2048 % 8 == 0
    const int swz = (bid & 7) * 256 + (bid >> 3); // bijective XCD chunking
    const int x0  = (swz & 15) << 7;
    const int y0  = ((swz >> 4) & 31) << 6;
    const int b   = swz >> 9;
    const int base = b * (HH * WW);               // int32 safe

    // stage: 16 dh bytes per lane-iter -> 16 squared u16 -> two b128 LDS writes
    for (int i = tid; i < 106 * 8; i += 256) {
        const int r   = i >> 3;
        const int c16 = (i & 7) << 4;
        const int gy  = y0 - 21 + r;
        uint4 pk0, pk1;
        if (gy >= 0 && gy < HH) {
            const uint8_t* p = dh + base + gy * WW + x0 + c16;
            uint4 u = *(const uint4*)p;
            #pragma unroll
            for (int h = 0; h < 4; ++h) {
                uint32_t word = (&u.x)[h];
                uint32_t e0 = word & 0xff, e1 = (word >> 8) & 0xff;
                uint32_t e2 = (word >> 16) & 0xff, e3 = word >> 24;
                uint32_t lo = (e0 * e0) | ((e1 * e1) << 16);
                uint32_t hi = (e2 * e2) | ((e3 * e3) << 16);
                if (h < 2) { (&pk0.x)[h * 2] = lo; (&pk0.x)[h * 2 + 1] = hi; }
                else       { (&pk1.x)[(h - 2) * 2] = lo; (&pk1.x)[(h - 2) * 2 + 1] = hi; }
            }
        } else {
            pk0.x = pk0.y = pk0.z = pk0.w = BIGSQ | (BIGSQ << 16);
            pk1 = pk0;
        }
        *(uint4*)&s[r][c16]     = pk0;
        *(uint4*)&s[r][c16 + 8] = pk1;
    }
    __syncthreads();

    const int lane = tid & 63;
    const int w    = tid >> 6;
    const int cg   = (lane & 31) << 2;   // 4 adjacent cols per lane
    const int rofs = lane >> 5;          // row offset 0/1
    for (int k = 0; k < 8; ++k) {
        const int j  = (w << 4) + (k << 1) + rofs;
        const int yl = 21 + j;

        uint2 q = *(const uint2*)&s[yl][cg];
        u16x2 V0 = __builtin_bit_cast(u16x2, q.x);
        u16x2 V1 = __builtin_bit_cast(u16x2, q.y);

        for (int d = 1; d <= MAXT; ++d) {
            const uint32_t dd = (uint32_t)(d * d);
            u16x2 M = __builtin_elementwise_max(V0, V1);
            uint32_t m32 = __builtin_bit_cast(uint32_t, M);
            uint32_t h = umax32(m32 & 0xffffu, m32 >> 16);
            if (__all(dd >= h)) break;   // further candidates >= d^2 >= current
            uint2 a  = *(const uint2*)&s[yl - d][cg];
            uint2 bq = *(const uint2*)&s[yl + d][cg];
            u16x2 D  = { (unsigned short)dd, (unsigned short)dd };
            u16x2 A0 = __builtin_bit_cast(u16x2, a.x),  A1 = __builtin_bit_cast(u16x2, a.y);
            u16x2 B0 = __builtin_bit_cast(u16x2, bq.x), B1 = __builtin_bit_cast(u16x2, bq.y);
            // min(A,B)+D == min(A+D, B+D); values <= 882, no u16 overflow
            V0 = __builtin_elementwise_min(V0, (u16x2)(__builtin_elementwise_min(A0, B0) + D));
            V1 = __builtin_elementwise_min(V1, (u16x2)(__builtin_elementwise_min(A1, B1) + D));
        }

        const uint32_t r0 = __builtin_bit_cast(uint32_t, V0);
        const uint32_t r1 = __builtin_bit_cast(uint32_t, V1);
        floatx4 o;
        o.x = sqrtf((float)(r0 & 0xffffu));
        o.y = sqrtf((float)(r0 >> 16));
        o.z = sqrtf((float)(r1 & 0xffffu));
        o.w = sqrtf((float)(r1 >> 16));
        floatx4* op = (floatx4*)&out[base + (y0 + j) * WW + x0 + cg];
        __builtin_nontemporal_store(o, op);
    }
}

extern "C" void kernel_launch(void* const* d_in, const int* in_sizes, int n_in,
                              void* d_out, int out_size, void* d_ws, size_t ws_size,
                              hipStream_t stream) {
    const int* unt = (const int*)d_in[0];
    uint8_t* dh    = (uint8_t*)d_ws;             // BB*HH*WW bytes = 16.7 MB scratch
    float* out     = (float*)d_out;

    hpass<<<dim3(BB * HH / 4), 256, 0, stream>>>(unt, dh);
    vpass<<<dim3(WW / 128 * HH / 64 * BB), 256, 0, stream>>>(dh, out);
}

// Round 13
// 38.718 us; speedup vs baseline: 3.7113x; 1.1800x over previous
//
#include <hip/hip_runtime.h>
#include <cstdint>

#define BB 4
#define HH 2048
#define WW 2048
#define MAXT 21
#define BIGSQ 441        // MAXT^2
#define SEN (1u << 6)    // sentinel bit: quad-dist t=6 -> d>=24 -> clamps to 21

typedef float floatx4 __attribute__((ext_vector_type(4)));
typedef unsigned short u16x2 __attribute__((ext_vector_type(2)));

static __device__ __forceinline__ uint32_t umax32(uint32_t a, uint32_t b) { return a > b ? a : b; }
static __device__ __forceinline__ int imin(int a, int b) { return a < b ? a : b; }

// ---------------- Pass A: horizontal capped nearest-obstacle distance ----------------
// One wave = one full row (2048 px), uint4 loads (16 B = 4 px per lane).
// R10-validated quad-phase ballot scheme, restructured so the load registers
// die immediately: all 8 loads -> all 32 ballots (q dead, masks in scalar
// regs) -> pure-ALU combine loop. Low peak VGPR => 8 waves/SIMD; no memory
// dependence in the loop => compiler cannot sink loads.
__global__ __launch_bounds__(256) void hpass(const int* __restrict__ in,
                                             uint8_t* __restrict__ dh) {
    const int tid  = threadIdx.x;
    const int lane = tid & 63;
    const int w    = tid >> 6;
    const int row  = (blockIdx.x << 2) + w;   // 4 rows per block; rows never cross batches
    const int ro   = row * WW;                 // < 2^24, int32 safe
    const int* rp  = in + ro;
    const int li   = 63 - lane;

    uint4 q[8];
    #pragma unroll
    for (int j = 0; j < 8; ++j)
        q[j] = *(const uint4*)(rp + (j << 8) + (lane << 2));

    // All ballots upfront: q dies here, masks are wave-uniform 64-bit values.
    unsigned long long B[9][4];
    #pragma unroll
    for (int j = 0; j < 8; ++j) {
        B[j][0] = __ballot(q[j].x != 0);
        B[j][1] = __ballot(q[j].y != 0);
        B[j][2] = __ballot(q[j].z != 0);
        B[j][3] = __ballot(q[j].w != 0);
    }
    #pragma unroll
    for (int k = 0; k < 4; ++k) B[8][k] = 0;

    #pragma unroll
    for (int j = 0; j < 8; ++j) {
        int a[4], b[4], c[4], e[4];
        #pragma unroll
        for (int k = 0; k < 4; ++k) {
            const unsigned long long Bc  = B[j][k];
            const unsigned long long Bn  = B[j + 1][k];
            const unsigned long long rbc = __brevll(Bc);
            const unsigned long long rbp = (j > 0) ? __brevll(B[j - 1][k]) : 0ull;
            unsigned long long S  = (Bc >> lane)  | ((Bn << 1) << li);
            unsigned long long SL = (rbc >> li)   | ((rbp << 1) << lane);
            uint32_t s  = (uint32_t)S;
            uint32_t sl = (uint32_t)SL;
            a[k] = 4 * __builtin_ctz(s | SEN) + k;
            b[k] = 4 * __builtin_ctz((s >> 1) | SEN) + 4 + k;
            c[k] = 4 * __builtin_ctz(sl | SEN) - k;
            e[k] = 4 * __builtin_ctz((sl >> 1) | SEN) + 4 - k;
        }
        const int A3 = a[3], A2 = imin(a[2], A3), A1 = imin(a[1], A2), A0 = imin(a[0], A1);
        const int B0 = b[0], B1 = imin(B0, b[1]), B2 = imin(B1, b[2]);
        const int C0 = c[0], C1 = imin(C0, c[1]), C2 = imin(C1, c[2]), C3 = imin(C2, c[3]);
        const int E3 = e[3], E2 = imin(e[2], E3), E1 = imin(e[1], E2);

        int d0 = imin(imin(A0,               imin(C0, E1)    ), MAXT);
        int d1 = imin(imin(imin(A1, B0) - 1, imin(C1, E2) + 1), MAXT);
        int d2 = imin(imin(imin(A2, B1) - 2, imin(C2, E3) + 2), MAXT);
        int d3 = imin(imin(imin(A3, B2) - 3, C3 + 3          ), MAXT);

        uint32_t pk = (uint32_t)d0 | ((uint32_t)d1 << 8) | ((uint32_t)d2 << 16) | ((uint32_t)d3 << 24);
        *(uint32_t*)(dh + ro + (j << 8) + (lane << 2)) = pk;
    }
}

// ---------------- Pass B: vertical relax + sqrt (R10-validated, unchanged) ----------------
__global__ __launch_bounds__(256) void vpass(const uint8_t* __restrict__ dh,
                                             float* __restrict__ out) {
    __shared__ uint16_t s[106][128];   // 27136 B
    const int tid = threadIdx.x;
    const int bid = blockIdx.x;                   // 2048 blocks, 2048 % 8 == 0
    const int swz = (bid & 7) * 256 + (bid >> 3); // bijective XCD chunking
    const int x0  = (swz & 15) << 7;
    const int y0  = ((swz >> 4) & 31) << 6;
    const int b   = swz >> 9;
    const int base = b * (HH * WW);               // int32 safe

    // stage: 16 dh bytes per lane-iter -> 16 squared u16 -> two b128 LDS writes
    for (int i = tid; i < 106 * 8; i += 256) {
        const int r   = i >> 3;
        const int c16 = (i & 7) << 4;
        const int gy  = y0 - 21 + r;
        uint4 pk0, pk1;
        if (gy >= 0 && gy < HH) {
            const uint8_t* p = dh + base + gy * WW + x0 + c16;
            uint4 u = *(const uint4*)p;
            #pragma unroll
            for (int h = 0; h < 4; ++h) {
                uint32_t word = (&u.x)[h];
                uint32_t e0 = word & 0xff, e1 = (word >> 8) & 0xff;
                uint32_t e2 = (word >> 16) & 0xff, e3 = word >> 24;
                uint32_t lo = (e0 * e0) | ((e1 * e1) << 16);
                uint32_t hi = (e2 * e2) | ((e3 * e3) << 16);
                if (h < 2) { (&pk0.x)[h * 2] = lo; (&pk0.x)[h * 2 + 1] = hi; }
                else       { (&pk1.x)[(h - 2) * 2] = lo; (&pk1.x)[(h - 2) * 2 + 1] = hi; }
            }
        } else {
            pk0.x = pk0.y = pk0.z = pk0.w = BIGSQ | (BIGSQ << 16);
            pk1 = pk0;
        }
        *(uint4*)&s[r][c16]     = pk0;
        *(uint4*)&s[r][c16 + 8] = pk1;
    }
    __syncthreads();

    const int lane = tid & 63;
    const int w    = tid >> 6;
    const int cg   = (lane & 31) << 2;   // 4 adjacent cols per lane
    const int rofs = lane >> 5;          // row offset 0/1
    for (int k = 0; k < 8; ++k) {
        const int j  = (w << 4) + (k << 1) + rofs;
        const int yl = 21 + j;

        uint2 q = *(const uint2*)&s[yl][cg];
        u16x2 V0 = __builtin_bit_cast(u16x2, q.x);
        u16x2 V1 = __builtin_bit_cast(u16x2, q.y);

        for (int d = 1; d <= MAXT; ++d) {
            const uint32_t dd = (uint32_t)(d * d);
            u16x2 M = __builtin_elementwise_max(V0, V1);
            uint32_t m32 = __builtin_bit_cast(uint32_t, M);
            uint32_t h = umax32(m32 & 0xffffu, m32 >> 16);
            if (__all(dd >= h)) break;   // further candidates >= d^2 >= current
            uint2 a  = *(const uint2*)&s[yl - d][cg];
            uint2 bq = *(const uint2*)&s[yl + d][cg];
            u16x2 D  = { (unsigned short)dd, (unsigned short)dd };
            u16x2 A0 = __builtin_bit_cast(u16x2, a.x),  A1 = __builtin_bit_cast(u16x2, a.y);
            u16x2 B0 = __builtin_bit_cast(u16x2, bq.x), B1 = __builtin_bit_cast(u16x2, bq.y);
            // min(A,B)+D == min(A+D, B+D); values <= 882, no u16 overflow
            V0 = __builtin_elementwise_min(V0, (u16x2)(__builtin_elementwise_min(A0, B0) + D));
            V1 = __builtin_elementwise_min(V1, (u16x2)(__builtin_elementwise_min(A1, B1) + D));
        }

        const uint32_t r0 = __builtin_bit_cast(uint32_t, V0);
        const uint32_t r1 = __builtin_bit_cast(uint32_t, V1);
        floatx4 o;
        o.x = sqrtf((float)(r0 & 0xffffu));
        o.y = sqrtf((float)(r0 >> 16));
        o.z = sqrtf((float)(r1 & 0xffffu));
        o.w = sqrtf((float)(r1 >> 16));
        floatx4* op = (floatx4*)&out[base + (y0 + j) * WW + x0 + cg];
        __builtin_nontemporal_store(o, op);
    }
}

extern "C" void kernel_launch(void* const* d_in, const int* in_sizes, int n_in,
                              void* d_out, int out_size, void* d_ws, size_t ws_size,
                              hipStream_t stream) {
    const int* unt = (const int*)d_in[0];
    uint8_t* dh    = (uint8_t*)d_ws;             // BB*HH*WW bytes = 16.7 MB scratch
    float* out     = (float*)d_out;

    hpass<<<dim3(BB * HH / 4), 256, 0, stream>>>(unt, dh);
    vpass<<<dim3(WW / 128 * HH / 64 * BB), 256, 0, stream>>>(dh, out);
}